// Round 17
// baseline (224.554 us; speedup 1.0000x reference)
//
#include <hip/hip_runtime.h>
#include <hip/hip_bf16.h>

using bf16 = __hip_bfloat16;
typedef __attribute__((ext_vector_type(8))) short short8;
typedef __attribute__((ext_vector_type(4))) float f32x4;

#define ZN 4096
#define KN 48

// tanh-form GELU (validated R14): max |diff vs erf-gelu| ~3e-4.
__device__ __forceinline__ float gelu_f(float x) {
    float t = x * x;
    float z = x * fmaf(0.07135481627f, t, 1.595769122f);
    return x / (1.0f + __expf(-z));
}

__device__ __forceinline__ uint2 pack4(float a, float b, float c, float d) {
    union { bf16 h[4]; uint2 u; } t;
    t.h[0] = __float2bfloat16(a); t.h[1] = __float2bfloat16(b);
    t.h[2] = __float2bfloat16(c); t.h[3] = __float2bfloat16(d);
    return t.u;
}

__device__ __forceinline__ f32x4 splat4(float v) {
    f32x4 r; r[0] = v; r[1] = v; r[2] = v; r[3] = v; return r;
}

// Merged pack: six msg W[K][128] (B-frag NT=8) + ffn w1 [128][512] (NT=32) + w2 [512][128] (NT=8).
__global__ void pack_combined_kernel(const float* __restrict__ nm1, const float* __restrict__ nm2,
                                     const float* __restrict__ nm3, const float* __restrict__ em1,
                                     const float* __restrict__ em2, const float* __restrict__ em3,
                                     const float* __restrict__ fw1, const float* __restrict__ fw2,
                                     bf16* __restrict__ P, bf16* __restrict__ P1, bf16* __restrict__ P2) {
    int idx = blockIdx.x * 256 + threadIdx.x;          // 0 .. 294911
    if (idx < 163840) {
        const float* W; int local;
        if      (idx <  49152) { W = nm1; local = idx;          }
        else if (idx <  65536) { W = nm2; local = idx -  49152; }
        else if (idx <  81920) { W = nm3; local = idx -  65536; }
        else if (idx < 131072) { W = em1; local = idx -  81920; }
        else if (idx < 147456) { W = em2; local = idx - 131072; }
        else                   { W = em3; local = idx - 147456; }
        int j    = local & 7;
        int lane = (local >> 3) & 63;
        int nt   = (local >> 9) & 7;
        int ks   = local >> 12;
        int k = ks * 32 + ((lane >> 4) << 3) + j;
        int n = nt * 16 + (lane & 15);
        P[local + (idx - local)] = __float2bfloat16(W[k * 128 + n]);   // P is contiguous: idx
    } else if (idx < 163840 + 65536) {
        int local = idx - 163840;
        int j = local & 7, lane = (local >> 3) & 63, nt = (local >> 9) & 31, ks = local >> 14;
        int k = ks * 32 + ((lane >> 4) << 3) + j;
        int n = nt * 16 + (lane & 15);
        P1[local] = __float2bfloat16(fw1[k * 512 + n]);
    } else {
        int local = idx - 163840 - 65536;
        int j = local & 7, lane = (local >> 3) & 63, nt = (local >> 9) & 7, ks = local >> 12;
        int k = ks * 32 + ((lane >> 4) << 3) + j;
        int n = nt * 16 + (lane & 15);
        P2[local] = __float2bfloat16(fw2[k * 128 + n]);
    }
}

// 3-Mtile GEMM stage (msg kernels): A [48][ldA] bf16 in LDS, B packed (NT=8).
template<int KSBEG, int NSTEPS>
__device__ __forceinline__ void do_gemm(const bf16* A, int ldA, const bf16* Bp,
                                        int lane, int nt0, f32x4 acc[3][2]) {
    #pragma unroll
    for (int s = 0; s < NSTEPS; ++s) {
        int ks = KSBEG + s;
        short8 b0 = *(const short8*)(Bp + (((ks * 8 + nt0) * 64 + lane) << 3));
        short8 b1 = *(const short8*)(Bp + (((ks * 8 + nt0 + 1) * 64 + lane) << 3));
        int kcol = s * 32 + ((lane >> 4) << 3);
        #pragma unroll
        for (int mt = 0; mt < 3; ++mt) {
            short8 a = *(const short8*)(A + (mt * 16 + (lane & 15)) * ldA + kcol);
            acc[mt][0] = __builtin_amdgcn_mfma_f32_16x16x32_bf16(a, b0, acc[mt][0], 0, 0, 0);
            acc[mt][1] = __builtin_amdgcn_mfma_f32_16x16x32_bf16(a, b1, acc[mt][1], 0, 0, 0);
        }
    }
}

// 1-Mtile GEMM stage: A [16][ldA] bf16 in LDS, B packed with NT n-tiles per ks.
template<int NSTEPS, int NT, int NACC>
__device__ __forceinline__ void do_gemm_1m(const bf16* A, int ldA, const bf16* Bp,
                                           int lane, int nt0, f32x4 acc[NACC]) {
    #pragma unroll
    for (int s = 0; s < NSTEPS; ++s) {
        int kcol = s * 32 + ((lane >> 4) << 3);
        short8 a = *(const short8*)(A + (lane & 15) * ldA + kcol);
        #pragma unroll
        for (int ni = 0; ni < NACC; ++ni) {
            short8 b = *(const short8*)(Bp + (((s * NT + nt0 + ni) * 64 + lane) << 3));
            acc[ni] = __builtin_amdgcn_mfma_f32_16x16x32_bf16(a, b, acc[ni], 0, 0, 0);
        }
    }
}

// Yvi[n][:] = b1 + Vsrc[n]@w1[0:128,:] via MFMA (node pass only).
__global__ __launch_bounds__(256, 4)
void yvi_mfma_kernel(const float* __restrict__ Vsrc, const bf16* __restrict__ w1p,
                     const float* __restrict__ b1f, bf16* __restrict__ out)
{
    __shared__ __align__(16) bf16 sA[16][136];
    const int nb  = blockIdx.x * 16;
    const int tid = threadIdx.x;
    const int lane = tid & 63, wid = tid >> 6;
    for (int c = tid; c < 16 * 32; c += 256) {
        int r = c >> 5, off = (c & 31) * 4;
        float4 v = *(const float4*)(Vsrc + (size_t)(nb + r) * 128 + off);
        *(uint2*)&sA[r][off] = pack4(v.x, v.y, v.z, v.w);
    }
    __syncthreads();
    const int nt0 = wid * 2;
    f32x4 acc[2];
    acc[0] = (f32x4){0.f,0.f,0.f,0.f}; acc[1] = (f32x4){0.f,0.f,0.f,0.f};
    do_gemm_1m<4, 8, 2>(&sA[0][0], 136, w1p, lane, nt0, acc);
    const int lm = lane & 15, lg = lane >> 4;
    #pragma unroll
    for (int ni = 0; ni < 2; ++ni) {
        int col = (nt0 + ni) * 16 + lm;
        float bv = b1f[col];
        #pragma unroll
        for (int r = 0; r < 4; ++r)
            out[(size_t)(nb + lg * 4 + r) * 128 + col] = __float2bfloat16(acc[ni][r] + bv);
    }
}

// FFN via MFMA + FUSED yviE (validated R16).
__global__ __launch_bounds__(256, 2)
void ffn_mfma_kernel(const bf16* __restrict__ V1,
                     const bf16* __restrict__ w1p, const float* __restrict__ b1,
                     const bf16* __restrict__ w2p, const float* __restrict__ b2,
                     const float* __restrict__ g, const float* __restrict__ bta,
                     const bf16* __restrict__ ew1p, const float* __restrict__ eb1,
                     float* __restrict__ Vout, bf16* __restrict__ YviE,
                     bf16* __restrict__ V2b)
{
    __shared__ __align__(16) bf16 sA[16][136];
    __shared__ __align__(16) bf16 sH[16][520];
    __shared__ float sX[16][132];
    const int nb  = blockIdx.x * 16;
    const int tid = threadIdx.x;
    const int lane = tid & 63, wid = tid >> 6;
    const int lm = lane & 15, lg = lane >> 4;
    const int nt0 = wid * 2;
    {
        int c = tid;
        int r = c >> 4, off = (c & 15) * 8;
        *(uint4*)&sA[r][off] = *(const uint4*)(V1 + (size_t)(nb + r) * 128 + off);
    }
    __syncthreads();
    {
        f32x4 acc[8];
        #pragma unroll
        for (int i = 0; i < 8; ++i) acc[i] = splat4(b1[(wid * 8 + i) * 16 + lm]);
        do_gemm_1m<4, 32, 8>(&sA[0][0], 136, w1p, lane, wid * 8, acc);
        #pragma unroll
        for (int ni = 0; ni < 8; ++ni) {
            int col = (wid * 8 + ni) * 16 + lm;
            #pragma unroll
            for (int r = 0; r < 4; ++r)
                sH[lg * 4 + r][col] = __float2bfloat16(gelu_f(acc[ni][r]));
        }
    }
    __syncthreads();
    {
        f32x4 acc[2];
        acc[0] = splat4(b2[wid * 32 + lm]); acc[1] = splat4(b2[wid * 32 + 16 + lm]);
        do_gemm_1m<16, 8, 2>(&sH[0][0], 520, w2p, lane, wid * 2, acc);
        #pragma unroll
        for (int ni = 0; ni < 2; ++ni) {
            int col = (wid * 2 + ni) * 16 + lm;
            #pragma unroll
            for (int r = 0; r < 4; ++r) {
                int row = lg * 4 + r;
                sX[row][col] = __bfloat162float(sA[row][col]) + acc[ni][r];
            }
        }
    }
    __syncthreads();
    for (int n = wid; n < 16; n += 4) {
        float a = sX[n][lane], b = sX[n][lane + 64];
        float s = a + b, q = a * a + b * b;
        #pragma unroll
        for (int off = 32; off; off >>= 1) { s += __shfl_xor(s, off); q += __shfl_xor(q, off); }
        float mean = s * (1.f / 128.f);
        float var  = q * (1.f / 128.f) - mean * mean;
        float rs   = rsqrtf(var + 1e-5f);
        size_t base = (size_t)(nb + n) * 128;
        float y0 = (a - mean) * rs * g[lane]      + bta[lane];
        float y1 = (b - mean) * rs * g[lane + 64] + bta[lane + 64];
        Vout[base + lane]      = y0;
        Vout[base + lane + 64] = y1;
        bf16 h0 = __float2bfloat16(y0), h1 = __float2bfloat16(y1);
        V2b[base + lane]      = h0;
        V2b[base + lane + 64] = h1;
        sA[n][lane]      = h0;
        sA[n][lane + 64] = h1;
    }
    __syncthreads();
    {
        f32x4 acc[2];
        acc[0] = splat4(eb1[nt0 * 16 + lm]);
        acc[1] = splat4(eb1[(nt0 + 1) * 16 + lm]);
        do_gemm_1m<4, 8, 2>(&sA[0][0], 136, ew1p, lane, nt0, acc);
        #pragma unroll
        for (int ni = 0; ni < 2; ++ni) {
            int col = (nt0 + ni) * 16 + lm;
            #pragma unroll
            for (int r = 0; r < 4; ++r)
                YviE[(size_t)(nb + lg * 4 + r) * 128 + col] = __float2bfloat16(acc[ni][r]);
        }
    }
}

// NODE message pass (validated R15/R16).
__global__ __launch_bounds__(256, 6)
void msg_node_kernel(const float* __restrict__ Vf,
                     const float* __restrict__ Ef,
                     const float* __restrict__ maskf,
                     const int*   __restrict__ Kidx,
                     const bf16*  __restrict__ Yvi,
                     const bf16* __restrict__ w1p,
                     const bf16* __restrict__ w2p, const float* __restrict__ b2f,
                     const bf16* __restrict__ w3p, const float* __restrict__ b3f,
                     const float* __restrict__ lng, const float* __restrict__ lnb,
                     const float* __restrict__ Vres,
                     bf16*  __restrict__ V1out)
{
    __shared__ __align__(16) char region0[26112];
    __shared__ float sMask[48];
    __shared__ bf16  sS[128];

    bf16  (*sA)[264]  = reinterpret_cast<bf16(*)[264]>(region0);
    bf16  (*sH1)[136] = reinterpret_cast<bf16(*)[136]>(region0);
    bf16  (*sH2)[136] = reinterpret_cast<bf16(*)[136]>(region0 + 13056);

    const int node = blockIdx.x;
    const int tid  = threadIdx.x;
    const int lane = tid & 63;
    const int wid  = tid >> 6;
    const int z    = node >> 10;
    const int* krow = Kidx + node * KN;

    const int nt0 = wid * 2;
    const int lm  = lane & 15;
    const int lg  = lane >> 4;

    float yv0 = __bfloat162float(Yvi[(size_t)node * 128 + nt0 * 16 + lm]);
    float yv1 = __bfloat162float(Yvi[(size_t)node * 128 + (nt0 + 1) * 16 + lm]);

    if (tid < KN) sMask[tid] = maskf[(size_t)node * KN + tid];
    {
        const float* erow0 = Ef + (size_t)node * KN * 128;
        for (int c = tid; c < KN * 32; c += 256) {
            int r = c >> 5;
            int off = (c & 31) * 4;
            int kj = krow[r];
            float4 vj = *(const float4*)(Vf + ((size_t)(z * 1024 + kj)) * 128 + off);
            *(uint2*)&sA[r][off] = pack4(vj.x, vj.y, vj.z, vj.w);
            float4 ee = *(const float4*)(erow0 + r * 128 + off);
            *(uint2*)&sA[r][128 + off] = pack4(ee.x, ee.y, ee.z, ee.w);
        }
    }
    __syncthreads();                                   // B0: sA ready

    f32x4 acc[3][2];
    #pragma unroll
    for (int mt = 0; mt < 3; ++mt) { acc[mt][0] = splat4(yv0); acc[mt][1] = splat4(yv1); }
    do_gemm<4, 8>(&sA[0][0], 264, w1p, lane, nt0, acc);
    __syncthreads();                                   // B1
    #pragma unroll
    for (int mt = 0; mt < 3; ++mt)
    #pragma unroll
    for (int ni = 0; ni < 2; ++ni) {
        int col = (nt0 + ni) * 16 + lm;
        #pragma unroll
        for (int r = 0; r < 4; ++r) {
            int row = mt * 16 + lg * 4 + r;
            sH1[row][col] = __float2bfloat16(gelu_f(acc[mt][ni][r]));
        }
    }
    __syncthreads();                                   // B2

    {
        float bc0 = b2f[nt0 * 16 + lm];
        float bc1 = b2f[(nt0 + 1) * 16 + lm];
        #pragma unroll
        for (int mt = 0; mt < 3; ++mt) { acc[mt][0] = splat4(bc0); acc[mt][1] = splat4(bc1); }
    }
    do_gemm<0, 4>(&sH1[0][0], 136, w2p, lane, nt0, acc);
    #pragma unroll
    for (int mt = 0; mt < 3; ++mt)
    #pragma unroll
    for (int r = 0; r < 4; ++r) {
        int row = mt * 16 + lg * 4 + r;
        sH2[row][nt0 * 16 + lm]       = __float2bfloat16(gelu_f(acc[mt][0][r]));
        sH2[row][(nt0 + 1) * 16 + lm] = __float2bfloat16(gelu_f(acc[mt][1][r]));
    }
    __syncthreads();                                   // B3

    {
        float bc0 = b3f[nt0 * 16 + lm];
        float bc1 = b3f[(nt0 + 1) * 16 + lm];
        #pragma unroll
        for (int mt = 0; mt < 3; ++mt) { acc[mt][0] = splat4(bc0); acc[mt][1] = splat4(bc1); }
    }
    do_gemm<0, 4>(&sH2[0][0], 136, w3p, lane, nt0, acc);
    {
        float cs0 = 0.f, cs1 = 0.f;
        #pragma unroll
        for (int mt = 0; mt < 3; ++mt)
        #pragma unroll
        for (int r = 0; r < 4; ++r) {
            float m = sMask[mt * 16 + lg * 4 + r];
            cs0 += acc[mt][0][r] * m;
            cs1 += acc[mt][1][r] * m;
        }
        cs0 += __shfl_xor(cs0, 16); cs0 += __shfl_xor(cs0, 32);
        cs1 += __shfl_xor(cs1, 16); cs1 += __shfl_xor(cs1, 32);
        if (lane < 16) {
            sS[nt0 * 16 + lane]       = __float2bfloat16(cs0);
            sS[(nt0 + 1) * 16 + lane] = __float2bfloat16(cs1);
        }
    }
    __syncthreads();                                   // B5

    if (tid < 64) {
        float a = Vres[(size_t)node * 128 + tid]      + __bfloat162float(sS[tid]);
        float b = Vres[(size_t)node * 128 + tid + 64] + __bfloat162float(sS[tid + 64]);
        float s = a + b, q = a * a + b * b;
        #pragma unroll
        for (int off = 32; off; off >>= 1) { s += __shfl_xor(s, off); q += __shfl_xor(q, off); }
        float mean = s * (1.f / 128.f);
        float var  = q * (1.f / 128.f) - mean * mean;
        float rs   = rsqrtf(var + 1e-5f);
        V1out[(size_t)node * 128 + tid] =
            __float2bfloat16((a - mean) * rs * lng[tid] + lnb[tid]);
        V1out[(size_t)node * 128 + tid + 64] =
            __float2bfloat16((b - mean) * rs * lng[tid + 64] + lnb[tid + 64]);
    }
}

// EDGE MLP kernel with FUSED LN (validated R13-R16); epilogue E values hoisted to
// registers at kernel start (T14-style: load-early / use-late, hides L3 latency).
__global__ __launch_bounds__(256, 5)
void mlp_edge_kernel(const bf16*  __restrict__ V2b,
                     const float* __restrict__ Ef,
                     const float* __restrict__ maskf,
                     const int*   __restrict__ Kidx,
                     const bf16*  __restrict__ Yvi,
                     const bf16* __restrict__ w1p,
                     const bf16* __restrict__ w2p, const float* __restrict__ b2f,
                     const bf16* __restrict__ w3p, const float* __restrict__ b3f,
                     const float* __restrict__ lng, const float* __restrict__ lnb,
                     float* __restrict__ Eout)
{
    __shared__ __align__(16) char region0[26112];
    __shared__ float sMask[48];
    __shared__ float sPart[48][4][2];

    bf16  (*sA)[264]  = reinterpret_cast<bf16(*)[264]>(region0);
    bf16  (*sH1)[136] = reinterpret_cast<bf16(*)[136]>(region0);
    bf16  (*sH2)[136] = reinterpret_cast<bf16(*)[136]>(region0 + 13056);

    const int node = blockIdx.x;
    const int tid  = threadIdx.x;
    const int lane = tid & 63;
    const int wid  = tid >> 6;
    const int z    = node >> 10;
    const int* krow = Kidx + node * KN;

    const int nt0 = wid * 2;
    const int lm  = lane & 15;
    const int lg  = lane >> 4;

    float yv0 = __bfloat162float(Yvi[(size_t)node * 128 + nt0 * 16 + lm]);
    float yv1 = __bfloat162float(Yvi[(size_t)node * 128 + (nt0 + 1) * 16 + lm]);

    // T14 hoist: epilogue E values into registers NOW; consumed after GEMM3.
    float ev[3][4][2];
    {
        const float* erow0 = Ef + (size_t)node * KN * 128;
        #pragma unroll
        for (int mt = 0; mt < 3; ++mt)
        #pragma unroll
        for (int r = 0; r < 4; ++r) {
            int row = mt * 16 + lg * 4 + r;
            ev[mt][r][0] = erow0[row * 128 + nt0 * 16 + lm];
            ev[mt][r][1] = erow0[row * 128 + (nt0 + 1) * 16 + lm];
        }
    }

    if (tid < KN) sMask[tid] = maskf[(size_t)node * KN + tid];
    {
        const float* erow0 = Ef + (size_t)node * KN * 128;
        for (int c = tid; c < KN * 32; c += 256) {
            int r = c >> 5;
            int off = (c & 31) * 4;
            int kj = krow[r];
            *(uint2*)&sA[r][off] =
                *(const uint2*)(V2b + ((size_t)(z * 1024 + kj)) * 128 + off);
            float4 ee = *(const float4*)(erow0 + r * 128 + off);
            *(uint2*)&sA[r][128 + off] = pack4(ee.x, ee.y, ee.z, ee.w);
        }
    }
    __syncthreads();                                   // B0

    f32x4 acc[3][2];
    #pragma unroll
    for (int mt = 0; mt < 3; ++mt) { acc[mt][0] = splat4(yv0); acc[mt][1] = splat4(yv1); }
    do_gemm<4, 8>(&sA[0][0], 264, w1p, lane, nt0, acc);
    __syncthreads();                                   // B1
    #pragma unroll
    for (int mt = 0; mt < 3; ++mt)
    #pragma unroll
    for (int ni = 0; ni < 2; ++ni) {
        int col = (nt0 + ni) * 16 + lm;
        #pragma unroll
        for (int r = 0; r < 4; ++r) {
            int row = mt * 16 + lg * 4 + r;
            sH1[row][col] = __float2bfloat16(gelu_f(acc[mt][ni][r]));
        }
    }
    __syncthreads();                                   // B2

    {
        float bc0 = b2f[nt0 * 16 + lm];
        float bc1 = b2f[(nt0 + 1) * 16 + lm];
        #pragma unroll
        for (int mt = 0; mt < 3; ++mt) { acc[mt][0] = splat4(bc0); acc[mt][1] = splat4(bc1); }
    }
    do_gemm<0, 4>(&sH1[0][0], 136, w2p, lane, nt0, acc);
    #pragma unroll
    for (int mt = 0; mt < 3; ++mt)
    #pragma unroll
    for (int r = 0; r < 4; ++r) {
        int row = mt * 16 + lg * 4 + r;
        sH2[row][nt0 * 16 + lm]       = __float2bfloat16(gelu_f(acc[mt][0][r]));
        sH2[row][(nt0 + 1) * 16 + lm] = __float2bfloat16(gelu_f(acc[mt][1][r]));
    }
    __syncthreads();                                   // B3

    {
        float bc0 = b3f[nt0 * 16 + lm];
        float bc1 = b3f[(nt0 + 1) * 16 + lm];
        #pragma unroll
        for (int mt = 0; mt < 3; ++mt) { acc[mt][0] = splat4(bc0); acc[mt][1] = splat4(bc1); }
    }
    do_gemm<0, 4>(&sH2[0][0], 136, w3p, lane, nt0, acc);

    // ---- fused epilogue: x = E(reg) + Me*mask, per-row partials to sPart ----
    float xv[3][4][2];
    {
        #pragma unroll
        for (int mt = 0; mt < 3; ++mt)
        #pragma unroll
        for (int r = 0; r < 4; ++r) {
            int row = mt * 16 + lg * 4 + r;
            float m = sMask[row];
            float x0 = ev[mt][r][0] + acc[mt][0][r] * m;
            float x1 = ev[mt][r][1] + acc[mt][1][r] * m;
            xv[mt][r][0] = x0; xv[mt][r][1] = x1;
            float s = x0 + x1, q = x0 * x0 + x1 * x1;
            s += __shfl_xor(s, 1); q += __shfl_xor(q, 1);
            s += __shfl_xor(s, 2); q += __shfl_xor(q, 2);
            s += __shfl_xor(s, 4); q += __shfl_xor(q, 4);
            s += __shfl_xor(s, 8); q += __shfl_xor(q, 8);
            if (lm == 0) { sPart[row][wid][0] = s; sPart[row][wid][1] = q; }
        }
    }
    __syncthreads();                                   // B4

    {
        float g0 = lng[nt0 * 16 + lm],       b0 = lnb[nt0 * 16 + lm];
        float g1 = lng[(nt0 + 1) * 16 + lm], b1 = lnb[(nt0 + 1) * 16 + lm];
        float* orow0 = Eout + (size_t)node * KN * 128;
        #pragma unroll
        for (int mt = 0; mt < 3; ++mt)
        #pragma unroll
        for (int r = 0; r < 4; ++r) {
            int row = mt * 16 + lg * 4 + r;
            float s = sPart[row][0][0] + sPart[row][1][0] + sPart[row][2][0] + sPart[row][3][0];
            float q = sPart[row][0][1] + sPart[row][1][1] + sPart[row][2][1] + sPart[row][3][1];
            float mean = s * (1.f / 128.f);
            float var  = q * (1.f / 128.f) - mean * mean;
            float rs   = rsqrtf(var + 1e-5f);
            orow0[row * 128 + nt0 * 16 + lm]       = (xv[mt][r][0] - mean) * rs * g0 + b0;
            orow0[row * 128 + (nt0 + 1) * 16 + lm] = (xv[mt][r][1] - mean) * rs * g1 + b1;
        }
    }
}

extern "C" void kernel_launch(void* const* d_in, const int* in_sizes, int n_in,
                              void* d_out, int out_size, void* d_ws, size_t ws_size,
                              hipStream_t stream) {
    const float* V     = (const float*)d_in[0];
    const float* E     = (const float*)d_in[1];
    const float* emask = (const float*)d_in[2];
    const float* nm_w1 = (const float*)d_in[3];
    const float* nm_b1 = (const float*)d_in[4];
    const float* nm_w2 = (const float*)d_in[5];
    const float* nm_b2 = (const float*)d_in[6];
    const float* nm_w3 = (const float*)d_in[7];
    const float* nm_b3 = (const float*)d_in[8];
    const float* nmn_g = (const float*)d_in[9];
    const float* nmn_b = (const float*)d_in[10];
    const float* ffn_w1 = (const float*)d_in[11];
    const float* ffn_b1 = (const float*)d_in[12];
    const float* ffn_w2 = (const float*)d_in[13];
    const float* ffn_b2 = (const float*)d_in[14];
    const float* fn_g  = (const float*)d_in[15];
    const float* fn_b  = (const float*)d_in[16];
    const float* em_w1 = (const float*)d_in[17];
    const float* em_b1 = (const float*)d_in[18];
    const float* em_w2 = (const float*)d_in[19];
    const float* em_b2 = (const float*)d_in[20];
    const float* em_w3 = (const float*)d_in[21];
    const float* em_b3 = (const float*)d_in[22];
    const float* emn_g = (const float*)d_in[23];
    const float* emn_b = (const float*)d_in[24];
    const int*  K     = (const int*)d_in[25];

    // ws layout (proven footprint):
    //   [0, 327680)            packed msg weights (bf16, 6 segments)
    //   [327680, +1MB)         V1f (bf16) -- reused as YviE (written by ffn) after read
    //   [327680+1MB, +2MB)     YviN (bf16) -- reused as V2b (bf16) after msg_node
    char* ws = (char*)d_ws;
    bf16* Pall    = (bf16*)(ws);
    bf16* p_nm_w1 = (bf16*)(ws);
    bf16* p_nm_w2 = (bf16*)(ws + 98304);
    bf16* p_nm_w3 = (bf16*)(ws + 131072);
    bf16* p_em_w1 = (bf16*)(ws + 163840);
    bf16* p_em_w2 = (bf16*)(ws + 262144);
    bf16* p_em_w3 = (bf16*)(ws + 294912);
    bf16* V1f  = (bf16*)(ws + 327680);
    bf16* YviE = (bf16*)(ws + 327680);
    bf16* YviN = (bf16*)(ws + 327680 + 1048576);
    bf16* V2b  = (bf16*)(ws + 327680 + 1048576);

    float* V2out = (float*)d_out;                 // [4,1024,128] f32
    float* Eout  = (float*)d_out + 524288;        // [4,1024,48,128] f32

    // ffn packed weights staged in the TAIL of Eout (overwritten by mlp_edge's E write).
    bf16* fw1p = (bf16*)((float*)d_out + 25690112 - 65536);
    bf16* fw2p = (bf16*)((float*)d_out + 25690112 - 32768);

    pack_combined_kernel<<<1152, 256, 0, stream>>>(
        nm_w1, nm_w2, nm_w3, em_w1, em_w2, em_w3, ffn_w1, ffn_w2, Pall, fw1p, fw2p);

    yvi_mfma_kernel<<<ZN / 16, 256, 0, stream>>>(V, p_nm_w1, nm_b1, YviN);

    msg_node_kernel<<<ZN, 256, 0, stream>>>(
        V, E, emask, K, YviN,
        p_nm_w1, p_nm_w2, nm_b2, p_nm_w3, nm_b3,
        nmn_g, nmn_b, V, V1f);

    ffn_mfma_kernel<<<ZN / 16, 256, 0, stream>>>(
        V1f, fw1p, ffn_b1, fw2p, ffn_b2, fn_g, fn_b,
        p_em_w1, em_b1, V2out, YviE, V2b);

    mlp_edge_kernel<<<ZN, 256, 0, stream>>>(
        V2b, E, emask, K, YviE,
        p_em_w1, p_em_w2, em_b2, p_em_w3, em_b3,
        emn_g, emn_b, Eout);
}

// Round 18
// 165.470 us; speedup vs baseline: 1.3571x; 1.3571x over previous
//
#include <hip/hip_runtime.h>
#include <hip/hip_bf16.h>

using bf16 = __hip_bfloat16;
typedef __attribute__((ext_vector_type(8))) short short8;
typedef __attribute__((ext_vector_type(4))) float f32x4;

#define ZN 4096
#define KN 48

// tanh-form GELU (validated R14): max |diff vs erf-gelu| ~3e-4.
__device__ __forceinline__ float gelu_f(float x) {
    float t = x * x;
    float z = x * fmaf(0.07135481627f, t, 1.595769122f);
    return x / (1.0f + __expf(-z));
}

__device__ __forceinline__ uint2 pack4(float a, float b, float c, float d) {
    union { bf16 h[4]; uint2 u; } t;
    t.h[0] = __float2bfloat16(a); t.h[1] = __float2bfloat16(b);
    t.h[2] = __float2bfloat16(c); t.h[3] = __float2bfloat16(d);
    return t.u;
}

__device__ __forceinline__ f32x4 splat4(float v) {
    f32x4 r; r[0] = v; r[1] = v; r[2] = v; r[3] = v; return r;
}

// Merged pack: six msg W[K][128] (B-frag NT=8) + ffn w1 [128][512] (NT=32) + w2 [512][128] (NT=8).
__global__ void pack_combined_kernel(const float* __restrict__ nm1, const float* __restrict__ nm2,
                                     const float* __restrict__ nm3, const float* __restrict__ em1,
                                     const float* __restrict__ em2, const float* __restrict__ em3,
                                     const float* __restrict__ fw1, const float* __restrict__ fw2,
                                     bf16* __restrict__ P, bf16* __restrict__ P1, bf16* __restrict__ P2) {
    int idx = blockIdx.x * 256 + threadIdx.x;          // 0 .. 294911
    if (idx < 163840) {
        const float* W; int local;
        if      (idx <  49152) { W = nm1; local = idx;          }
        else if (idx <  65536) { W = nm2; local = idx -  49152; }
        else if (idx <  81920) { W = nm3; local = idx -  65536; }
        else if (idx < 131072) { W = em1; local = idx -  81920; }
        else if (idx < 147456) { W = em2; local = idx - 131072; }
        else                   { W = em3; local = idx - 147456; }
        int j    = local & 7;
        int lane = (local >> 3) & 63;
        int nt   = (local >> 9) & 7;
        int ks   = local >> 12;
        int k = ks * 32 + ((lane >> 4) << 3) + j;
        int n = nt * 16 + (lane & 15);
        P[idx] = __float2bfloat16(W[k * 128 + n]);
    } else if (idx < 163840 + 65536) {
        int local = idx - 163840;
        int j = local & 7, lane = (local >> 3) & 63, nt = (local >> 9) & 31, ks = local >> 14;
        int k = ks * 32 + ((lane >> 4) << 3) + j;
        int n = nt * 16 + (lane & 15);
        P1[local] = __float2bfloat16(fw1[k * 512 + n]);
    } else {
        int local = idx - 163840 - 65536;
        int j = local & 7, lane = (local >> 3) & 63, nt = (local >> 9) & 7, ks = local >> 12;
        int k = ks * 32 + ((lane >> 4) << 3) + j;
        int n = nt * 16 + (lane & 15);
        P2[local] = __float2bfloat16(fw2[k * 128 + n]);
    }
}

// 3-Mtile GEMM stage (msg kernels): A [48][ldA] bf16 in LDS, B packed (NT=8).
template<int KSBEG, int NSTEPS>
__device__ __forceinline__ void do_gemm(const bf16* A, int ldA, const bf16* Bp,
                                        int lane, int nt0, f32x4 acc[3][2]) {
    #pragma unroll
    for (int s = 0; s < NSTEPS; ++s) {
        int ks = KSBEG + s;
        short8 b0 = *(const short8*)(Bp + (((ks * 8 + nt0) * 64 + lane) << 3));
        short8 b1 = *(const short8*)(Bp + (((ks * 8 + nt0 + 1) * 64 + lane) << 3));
        int kcol = s * 32 + ((lane >> 4) << 3);
        #pragma unroll
        for (int mt = 0; mt < 3; ++mt) {
            short8 a = *(const short8*)(A + (mt * 16 + (lane & 15)) * ldA + kcol);
            acc[mt][0] = __builtin_amdgcn_mfma_f32_16x16x32_bf16(a, b0, acc[mt][0], 0, 0, 0);
            acc[mt][1] = __builtin_amdgcn_mfma_f32_16x16x32_bf16(a, b1, acc[mt][1], 0, 0, 0);
        }
    }
}

// 1-Mtile GEMM stage: A [16][ldA] bf16 in LDS, B packed with NT n-tiles per ks.
template<int NSTEPS, int NT, int NACC>
__device__ __forceinline__ void do_gemm_1m(const bf16* A, int ldA, const bf16* Bp,
                                           int lane, int nt0, f32x4 acc[NACC]) {
    #pragma unroll
    for (int s = 0; s < NSTEPS; ++s) {
        int kcol = s * 32 + ((lane >> 4) << 3);
        short8 a = *(const short8*)(A + (lane & 15) * ldA + kcol);
        #pragma unroll
        for (int ni = 0; ni < NACC; ++ni) {
            short8 b = *(const short8*)(Bp + (((s * NT + nt0 + ni) * 64 + lane) << 3));
            acc[ni] = __builtin_amdgcn_mfma_f32_16x16x32_bf16(a, b, acc[ni], 0, 0, 0);
        }
    }
}

// Yvi[n][:] = b1 + Vsrc[n]@w1[0:128,:] via MFMA (node pass only).
__global__ __launch_bounds__(256, 4)
void yvi_mfma_kernel(const float* __restrict__ Vsrc, const bf16* __restrict__ w1p,
                     const float* __restrict__ b1f, bf16* __restrict__ out)
{
    __shared__ __align__(16) bf16 sA[16][136];
    const int nb  = blockIdx.x * 16;
    const int tid = threadIdx.x;
    const int lane = tid & 63, wid = tid >> 6;
    for (int c = tid; c < 16 * 32; c += 256) {
        int r = c >> 5, off = (c & 31) * 4;
        float4 v = *(const float4*)(Vsrc + (size_t)(nb + r) * 128 + off);
        *(uint2*)&sA[r][off] = pack4(v.x, v.y, v.z, v.w);
    }
    __syncthreads();
    const int nt0 = wid * 2;
    f32x4 acc[2];
    acc[0] = (f32x4){0.f,0.f,0.f,0.f}; acc[1] = (f32x4){0.f,0.f,0.f,0.f};
    do_gemm_1m<4, 8, 2>(&sA[0][0], 136, w1p, lane, nt0, acc);
    const int lm = lane & 15, lg = lane >> 4;
    #pragma unroll
    for (int ni = 0; ni < 2; ++ni) {
        int col = (nt0 + ni) * 16 + lm;
        float bv = b1f[col];
        #pragma unroll
        for (int r = 0; r < 4; ++r)
            out[(size_t)(nb + lg * 4 + r) * 128 + col] = __float2bfloat16(acc[ni][r] + bv);
    }
}

// FFN via MFMA + FUSED yviE (validated R16).
__global__ __launch_bounds__(256, 2)
void ffn_mfma_kernel(const bf16* __restrict__ V1,
                     const bf16* __restrict__ w1p, const float* __restrict__ b1,
                     const bf16* __restrict__ w2p, const float* __restrict__ b2,
                     const float* __restrict__ g, const float* __restrict__ bta,
                     const bf16* __restrict__ ew1p, const float* __restrict__ eb1,
                     float* __restrict__ Vout, bf16* __restrict__ YviE,
                     bf16* __restrict__ V2b)
{
    __shared__ __align__(16) bf16 sA[16][136];
    __shared__ __align__(16) bf16 sH[16][520];
    __shared__ float sX[16][132];
    const int nb  = blockIdx.x * 16;
    const int tid = threadIdx.x;
    const int lane = tid & 63, wid = tid >> 6;
    const int lm = lane & 15, lg = lane >> 4;
    const int nt0 = wid * 2;
    {
        int c = tid;
        int r = c >> 4, off = (c & 15) * 8;
        *(uint4*)&sA[r][off] = *(const uint4*)(V1 + (size_t)(nb + r) * 128 + off);
    }
    __syncthreads();
    {
        f32x4 acc[8];
        #pragma unroll
        for (int i = 0; i < 8; ++i) acc[i] = splat4(b1[(wid * 8 + i) * 16 + lm]);
        do_gemm_1m<4, 32, 8>(&sA[0][0], 136, w1p, lane, wid * 8, acc);
        #pragma unroll
        for (int ni = 0; ni < 8; ++ni) {
            int col = (wid * 8 + ni) * 16 + lm;
            #pragma unroll
            for (int r = 0; r < 4; ++r)
                sH[lg * 4 + r][col] = __float2bfloat16(gelu_f(acc[ni][r]));
        }
    }
    __syncthreads();
    {
        f32x4 acc[2];
        acc[0] = splat4(b2[wid * 32 + lm]); acc[1] = splat4(b2[wid * 32 + 16 + lm]);
        do_gemm_1m<16, 8, 2>(&sH[0][0], 520, w2p, lane, wid * 2, acc);
        #pragma unroll
        for (int ni = 0; ni < 2; ++ni) {
            int col = (wid * 2 + ni) * 16 + lm;
            #pragma unroll
            for (int r = 0; r < 4; ++r) {
                int row = lg * 4 + r;
                sX[row][col] = __bfloat162float(sA[row][col]) + acc[ni][r];
            }
        }
    }
    __syncthreads();
    for (int n = wid; n < 16; n += 4) {
        float a = sX[n][lane], b = sX[n][lane + 64];
        float s = a + b, q = a * a + b * b;
        #pragma unroll
        for (int off = 32; off; off >>= 1) { s += __shfl_xor(s, off); q += __shfl_xor(q, off); }
        float mean = s * (1.f / 128.f);
        float var  = q * (1.f / 128.f) - mean * mean;
        float rs   = rsqrtf(var + 1e-5f);
        size_t base = (size_t)(nb + n) * 128;
        float y0 = (a - mean) * rs * g[lane]      + bta[lane];
        float y1 = (b - mean) * rs * g[lane + 64] + bta[lane + 64];
        Vout[base + lane]      = y0;
        Vout[base + lane + 64] = y1;
        bf16 h0 = __float2bfloat16(y0), h1 = __float2bfloat16(y1);
        V2b[base + lane]      = h0;
        V2b[base + lane + 64] = h1;
        sA[n][lane]      = h0;
        sA[n][lane + 64] = h1;
    }
    __syncthreads();
    {
        f32x4 acc[2];
        acc[0] = splat4(eb1[nt0 * 16 + lm]);
        acc[1] = splat4(eb1[(nt0 + 1) * 16 + lm]);
        do_gemm_1m<4, 8, 2>(&sA[0][0], 136, ew1p, lane, nt0, acc);
        #pragma unroll
        for (int ni = 0; ni < 2; ++ni) {
            int col = (nt0 + ni) * 16 + lm;
            #pragma unroll
            for (int r = 0; r < 4; ++r)
                YviE[(size_t)(nb + lg * 4 + r) * 128 + col] = __float2bfloat16(acc[ni][r]);
        }
    }
}

// NODE message pass (validated R15/R16).
__global__ __launch_bounds__(256, 6)
void msg_node_kernel(const float* __restrict__ Vf,
                     const float* __restrict__ Ef,
                     const float* __restrict__ maskf,
                     const int*   __restrict__ Kidx,
                     const bf16*  __restrict__ Yvi,
                     const bf16* __restrict__ w1p,
                     const bf16* __restrict__ w2p, const float* __restrict__ b2f,
                     const bf16* __restrict__ w3p, const float* __restrict__ b3f,
                     const float* __restrict__ lng, const float* __restrict__ lnb,
                     const float* __restrict__ Vres,
                     bf16*  __restrict__ V1out)
{
    __shared__ __align__(16) char region0[26112];
    __shared__ float sMask[48];
    __shared__ bf16  sS[128];

    bf16  (*sA)[264]  = reinterpret_cast<bf16(*)[264]>(region0);
    bf16  (*sH1)[136] = reinterpret_cast<bf16(*)[136]>(region0);
    bf16  (*sH2)[136] = reinterpret_cast<bf16(*)[136]>(region0 + 13056);

    const int node = blockIdx.x;
    const int tid  = threadIdx.x;
    const int lane = tid & 63;
    const int wid  = tid >> 6;
    const int z    = node >> 10;
    const int* krow = Kidx + node * KN;

    const int nt0 = wid * 2;
    const int lm  = lane & 15;
    const int lg  = lane >> 4;

    float yv0 = __bfloat162float(Yvi[(size_t)node * 128 + nt0 * 16 + lm]);
    float yv1 = __bfloat162float(Yvi[(size_t)node * 128 + (nt0 + 1) * 16 + lm]);

    if (tid < KN) sMask[tid] = maskf[(size_t)node * KN + tid];
    {
        const float* erow0 = Ef + (size_t)node * KN * 128;
        for (int c = tid; c < KN * 32; c += 256) {
            int r = c >> 5;
            int off = (c & 31) * 4;
            int kj = krow[r];
            float4 vj = *(const float4*)(Vf + ((size_t)(z * 1024 + kj)) * 128 + off);
            *(uint2*)&sA[r][off] = pack4(vj.x, vj.y, vj.z, vj.w);
            float4 ee = *(const float4*)(erow0 + r * 128 + off);
            *(uint2*)&sA[r][128 + off] = pack4(ee.x, ee.y, ee.z, ee.w);
        }
    }
    __syncthreads();                                   // B0: sA ready

    f32x4 acc[3][2];
    #pragma unroll
    for (int mt = 0; mt < 3; ++mt) { acc[mt][0] = splat4(yv0); acc[mt][1] = splat4(yv1); }
    do_gemm<4, 8>(&sA[0][0], 264, w1p, lane, nt0, acc);
    __syncthreads();                                   // B1
    #pragma unroll
    for (int mt = 0; mt < 3; ++mt)
    #pragma unroll
    for (int ni = 0; ni < 2; ++ni) {
        int col = (nt0 + ni) * 16 + lm;
        #pragma unroll
        for (int r = 0; r < 4; ++r) {
            int row = mt * 16 + lg * 4 + r;
            sH1[row][col] = __float2bfloat16(gelu_f(acc[mt][ni][r]));
        }
    }
    __syncthreads();                                   // B2

    {
        float bc0 = b2f[nt0 * 16 + lm];
        float bc1 = b2f[(nt0 + 1) * 16 + lm];
        #pragma unroll
        for (int mt = 0; mt < 3; ++mt) { acc[mt][0] = splat4(bc0); acc[mt][1] = splat4(bc1); }
    }
    do_gemm<0, 4>(&sH1[0][0], 136, w2p, lane, nt0, acc);
    #pragma unroll
    for (int mt = 0; mt < 3; ++mt)
    #pragma unroll
    for (int r = 0; r < 4; ++r) {
        int row = mt * 16 + lg * 4 + r;
        sH2[row][nt0 * 16 + lm]       = __float2bfloat16(gelu_f(acc[mt][0][r]));
        sH2[row][(nt0 + 1) * 16 + lm] = __float2bfloat16(gelu_f(acc[mt][1][r]));
    }
    __syncthreads();                                   // B3

    {
        float bc0 = b3f[nt0 * 16 + lm];
        float bc1 = b3f[(nt0 + 1) * 16 + lm];
        #pragma unroll
        for (int mt = 0; mt < 3; ++mt) { acc[mt][0] = splat4(bc0); acc[mt][1] = splat4(bc1); }
    }
    do_gemm<0, 4>(&sH2[0][0], 136, w3p, lane, nt0, acc);
    {
        float cs0 = 0.f, cs1 = 0.f;
        #pragma unroll
        for (int mt = 0; mt < 3; ++mt)
        #pragma unroll
        for (int r = 0; r < 4; ++r) {
            float m = sMask[mt * 16 + lg * 4 + r];
            cs0 += acc[mt][0][r] * m;
            cs1 += acc[mt][1][r] * m;
        }
        cs0 += __shfl_xor(cs0, 16); cs0 += __shfl_xor(cs0, 32);
        cs1 += __shfl_xor(cs1, 16); cs1 += __shfl_xor(cs1, 32);
        if (lane < 16) {
            sS[nt0 * 16 + lane]       = __float2bfloat16(cs0);
            sS[(nt0 + 1) * 16 + lane] = __float2bfloat16(cs1);
        }
    }
    __syncthreads();                                   // B5

    if (tid < 64) {
        float a = Vres[(size_t)node * 128 + tid]      + __bfloat162float(sS[tid]);
        float b = Vres[(size_t)node * 128 + tid + 64] + __bfloat162float(sS[tid + 64]);
        float s = a + b, q = a * a + b * b;
        #pragma unroll
        for (int off = 32; off; off >>= 1) { s += __shfl_xor(s, off); q += __shfl_xor(q, off); }
        float mean = s * (1.f / 128.f);
        float var  = q * (1.f / 128.f) - mean * mean;
        float rs   = rsqrtf(var + 1e-5f);
        V1out[(size_t)node * 128 + tid] =
            __float2bfloat16((a - mean) * rs * lng[tid] + lnb[tid]);
        V1out[(size_t)node * 128 + tid + 64] =
            __float2bfloat16((b - mean) * rs * lng[tid + 64] + lnb[tid + 64]);
    }
}

// EDGE MLP kernel with FUSED LN — R16-exact (epilogue E read from L2 post-GEMM3;
// NO register hoist: R17 proved the long-lived ev[] array spills to scratch).
__global__ __launch_bounds__(256, 5)
void mlp_edge_kernel(const bf16*  __restrict__ V2b,
                     const float* __restrict__ Ef,
                     const float* __restrict__ maskf,
                     const int*   __restrict__ Kidx,
                     const bf16*  __restrict__ Yvi,
                     const bf16* __restrict__ w1p,
                     const bf16* __restrict__ w2p, const float* __restrict__ b2f,
                     const bf16* __restrict__ w3p, const float* __restrict__ b3f,
                     const float* __restrict__ lng, const float* __restrict__ lnb,
                     float* __restrict__ Eout)
{
    __shared__ __align__(16) char region0[26112];
    __shared__ float sMask[48];
    __shared__ float sPart[48][4][2];

    bf16  (*sA)[264]  = reinterpret_cast<bf16(*)[264]>(region0);
    bf16  (*sH1)[136] = reinterpret_cast<bf16(*)[136]>(region0);
    bf16  (*sH2)[136] = reinterpret_cast<bf16(*)[136]>(region0 + 13056);

    const int node = blockIdx.x;
    const int tid  = threadIdx.x;
    const int lane = tid & 63;
    const int wid  = tid >> 6;
    const int z    = node >> 10;
    const int* krow = Kidx + node * KN;

    const int nt0 = wid * 2;
    const int lm  = lane & 15;
    const int lg  = lane >> 4;

    float yv0 = __bfloat162float(Yvi[(size_t)node * 128 + nt0 * 16 + lm]);
    float yv1 = __bfloat162float(Yvi[(size_t)node * 128 + (nt0 + 1) * 16 + lm]);

    if (tid < KN) sMask[tid] = maskf[(size_t)node * KN + tid];
    {
        const float* erow0 = Ef + (size_t)node * KN * 128;
        for (int c = tid; c < KN * 32; c += 256) {
            int r = c >> 5;
            int off = (c & 31) * 4;
            int kj = krow[r];
            *(uint2*)&sA[r][off] =
                *(const uint2*)(V2b + ((size_t)(z * 1024 + kj)) * 128 + off);
            float4 ee = *(const float4*)(erow0 + r * 128 + off);
            *(uint2*)&sA[r][128 + off] = pack4(ee.x, ee.y, ee.z, ee.w);
        }
    }
    __syncthreads();                                   // B0

    f32x4 acc[3][2];
    #pragma unroll
    for (int mt = 0; mt < 3; ++mt) { acc[mt][0] = splat4(yv0); acc[mt][1] = splat4(yv1); }
    do_gemm<4, 8>(&sA[0][0], 264, w1p, lane, nt0, acc);
    __syncthreads();                                   // B1
    #pragma unroll
    for (int mt = 0; mt < 3; ++mt)
    #pragma unroll
    for (int ni = 0; ni < 2; ++ni) {
        int col = (nt0 + ni) * 16 + lm;
        #pragma unroll
        for (int r = 0; r < 4; ++r) {
            int row = mt * 16 + lg * 4 + r;
            sH1[row][col] = __float2bfloat16(gelu_f(acc[mt][ni][r]));
        }
    }
    __syncthreads();                                   // B2

    {
        float bc0 = b2f[nt0 * 16 + lm];
        float bc1 = b2f[(nt0 + 1) * 16 + lm];
        #pragma unroll
        for (int mt = 0; mt < 3; ++mt) { acc[mt][0] = splat4(bc0); acc[mt][1] = splat4(bc1); }
    }
    do_gemm<0, 4>(&sH1[0][0], 136, w2p, lane, nt0, acc);
    #pragma unroll
    for (int mt = 0; mt < 3; ++mt)
    #pragma unroll
    for (int r = 0; r < 4; ++r) {
        int row = mt * 16 + lg * 4 + r;
        sH2[row][nt0 * 16 + lm]       = __float2bfloat16(gelu_f(acc[mt][0][r]));
        sH2[row][(nt0 + 1) * 16 + lm] = __float2bfloat16(gelu_f(acc[mt][1][r]));
    }
    __syncthreads();                                   // B3

    {
        float bc0 = b3f[nt0 * 16 + lm];
        float bc1 = b3f[(nt0 + 1) * 16 + lm];
        #pragma unroll
        for (int mt = 0; mt < 3; ++mt) { acc[mt][0] = splat4(bc0); acc[mt][1] = splat4(bc1); }
    }
    do_gemm<0, 4>(&sH2[0][0], 136, w3p, lane, nt0, acc);

    // ---- fused epilogue: x = E + Me*mask (E re-read, L2-hot), partials to sPart ----
    float xv[3][4][2];
    {
        const float* erow0 = Ef + (size_t)node * KN * 128;
        #pragma unroll
        for (int mt = 0; mt < 3; ++mt)
        #pragma unroll
        for (int r = 0; r < 4; ++r) {
            int row = mt * 16 + lg * 4 + r;
            float m = sMask[row];
            float x0 = erow0[row * 128 + nt0 * 16 + lm]       + acc[mt][0][r] * m;
            float x1 = erow0[row * 128 + (nt0 + 1) * 16 + lm] + acc[mt][1][r] * m;
            xv[mt][r][0] = x0; xv[mt][r][1] = x1;
            float s = x0 + x1, q = x0 * x0 + x1 * x1;
            s += __shfl_xor(s, 1); q += __shfl_xor(q, 1);
            s += __shfl_xor(s, 2); q += __shfl_xor(q, 2);
            s += __shfl_xor(s, 4); q += __shfl_xor(q, 4);
            s += __shfl_xor(s, 8); q += __shfl_xor(q, 8);
            if (lm == 0) { sPart[row][wid][0] = s; sPart[row][wid][1] = q; }
        }
    }
    __syncthreads();                                   // B4

    {
        float g0 = lng[nt0 * 16 + lm],       b0 = lnb[nt0 * 16 + lm];
        float g1 = lng[(nt0 + 1) * 16 + lm], b1 = lnb[(nt0 + 1) * 16 + lm];
        float* orow0 = Eout + (size_t)node * KN * 128;
        #pragma unroll
        for (int mt = 0; mt < 3; ++mt)
        #pragma unroll
        for (int r = 0; r < 4; ++r) {
            int row = mt * 16 + lg * 4 + r;
            float s = sPart[row][0][0] + sPart[row][1][0] + sPart[row][2][0] + sPart[row][3][0];
            float q = sPart[row][0][1] + sPart[row][1][1] + sPart[row][2][1] + sPart[row][3][1];
            float mean = s * (1.f / 128.f);
            float var  = q * (1.f / 128.f) - mean * mean;
            float rs   = rsqrtf(var + 1e-5f);
            orow0[row * 128 + nt0 * 16 + lm]       = (xv[mt][r][0] - mean) * rs * g0 + b0;
            orow0[row * 128 + (nt0 + 1) * 16 + lm] = (xv[mt][r][1] - mean) * rs * g1 + b1;
        }
    }
}

extern "C" void kernel_launch(void* const* d_in, const int* in_sizes, int n_in,
                              void* d_out, int out_size, void* d_ws, size_t ws_size,
                              hipStream_t stream) {
    const float* V     = (const float*)d_in[0];
    const float* E     = (const float*)d_in[1];
    const float* emask = (const float*)d_in[2];
    const float* nm_w1 = (const float*)d_in[3];
    const float* nm_b1 = (const float*)d_in[4];
    const float* nm_w2 = (const float*)d_in[5];
    const float* nm_b2 = (const float*)d_in[6];
    const float* nm_w3 = (const float*)d_in[7];
    const float* nm_b3 = (const float*)d_in[8];
    const float* nmn_g = (const float*)d_in[9];
    const float* nmn_b = (const float*)d_in[10];
    const float* ffn_w1 = (const float*)d_in[11];
    const float* ffn_b1 = (const float*)d_in[12];
    const float* ffn_w2 = (const float*)d_in[13];
    const float* ffn_b2 = (const float*)d_in[14];
    const float* fn_g  = (const float*)d_in[15];
    const float* fn_b  = (const float*)d_in[16];
    const float* em_w1 = (const float*)d_in[17];
    const float* em_b1 = (const float*)d_in[18];
    const float* em_w2 = (const float*)d_in[19];
    const float* em_b2 = (const float*)d_in[20];
    const float* em_w3 = (const float*)d_in[21];
    const float* em_b3 = (const float*)d_in[22];
    const float* emn_g = (const float*)d_in[23];
    const float* emn_b = (const float*)d_in[24];
    const int*  K     = (const int*)d_in[25];

    // ws layout (proven footprint):
    //   [0, 327680)            packed msg weights (bf16, 6 segments)
    //   [327680, +1MB)         V1f (bf16) -- reused as YviE (written by ffn) after read
    //   [327680+1MB, +2MB)     YviN (bf16) -- reused as V2b (bf16) after msg_node
    char* ws = (char*)d_ws;
    bf16* Pall    = (bf16*)(ws);
    bf16* p_nm_w1 = (bf16*)(ws);
    bf16* p_nm_w2 = (bf16*)(ws + 98304);
    bf16* p_nm_w3 = (bf16*)(ws + 131072);
    bf16* p_em_w1 = (bf16*)(ws + 163840);
    bf16* p_em_w2 = (bf16*)(ws + 262144);
    bf16* p_em_w3 = (bf16*)(ws + 294912);
    bf16* V1f  = (bf16*)(ws + 327680);
    bf16* YviE = (bf16*)(ws + 327680);
    bf16* YviN = (bf16*)(ws + 327680 + 1048576);
    bf16* V2b  = (bf16*)(ws + 327680 + 1048576);

    float* V2out = (float*)d_out;                 // [4,1024,128] f32
    float* Eout  = (float*)d_out + 524288;        // [4,1024,48,128] f32

    // ffn packed weights staged in the TAIL of Eout (overwritten by mlp_edge's E write).
    bf16* fw1p = (bf16*)((float*)d_out + 25690112 - 65536);
    bf16* fw2p = (bf16*)((float*)d_out + 25690112 - 32768);

    pack_combined_kernel<<<1152, 256, 0, stream>>>(
        nm_w1, nm_w2, nm_w3, em_w1, em_w2, em_w3, ffn_w1, ffn_w2, Pall, fw1p, fw2p);

    yvi_mfma_kernel<<<ZN / 16, 256, 0, stream>>>(V, p_nm_w1, nm_b1, YviN);

    msg_node_kernel<<<ZN, 256, 0, stream>>>(
        V, E, emask, K, YviN,
        p_nm_w1, p_nm_w2, nm_b2, p_nm_w3, nm_b3,
        nmn_g, nmn_b, V, V1f);

    ffn_mfma_kernel<<<ZN / 16, 256, 0, stream>>>(
        V1f, fw1p, ffn_b1, fw2p, ffn_b2, fn_g, fn_b,
        p_em_w1, em_b1, V2out, YviE, V2b);

    mlp_edge_kernel<<<ZN, 256, 0, stream>>>(
        V2b, E, emask, K, YviE,
        p_em_w1, p_em_w2, em_b2, p_em_w3, em_b3,
        emn_g, emn_b, Eout);
}